// Round 19
// baseline (55.772 us; speedup 1.0000x reference)
//
#include <hip/hip_runtime.h>
#include <math.h>

#define KCOMP 32
#define DDIM 64
#define LOG_2PI 1.8378770664093453f

// W~ fragment-major layout: frag index f = (comp*2 + r)*5 + s, each frag is
// 1024 B = 64 lanes x 16 B (one half8 per lane). Per comp: 10 frags = 10240 B.
#define WFRAG_HALF8S 64
#define WCOMP_BYTES 10240

typedef _Float16 half8 __attribute__((ext_vector_type(8)));
typedef float floatx16 __attribute__((ext_vector_type(16)));
typedef float float2v __attribute__((ext_vector_type(2)));

__device__ inline float rdlane(float v, int l) {
    return __uint_as_float(__builtin_amdgcn_readlane(__float_as_uint(v), l));
}

// ---------------------------------------------------------------------------
// 8-way split-c cooperative fused Cholesky+inverse step (template J).
// Wave g owns subset c = g + 8i (i=0..7) of every row's fused dot:
//   chol: dot_t += L[t][c] * L[J][c]     (LM[i].x pairs)
//   inv : ms_t  += L[J][c] * M[c][t]     (LM[i].y pairs)
// Always 8 terms (zero-padded exact: LM zero-init, col c written only at
// step c by its owner wave). Partial (dot, ms) -> LDS [parity][g][t],
// one barrier, 8-way reduce per lane, owner wave (g == J&7, uniform branch)
// writes LM[J>>3] and captures the diagonal. All register indices are
// compile-time. Per-wave streamed body ~4x smaller than the 1-wave R16
// version while keeping register/readlane operands (both measured-critical).
// ---------------------------------------------------------------------------
template <int J>
__device__ __forceinline__ void fused_step(const float (&Srow)[DDIM], float2v (&LM)[8],
                                           float2v* __restrict__ pbuf, float& mydiag,
                                           const int t, const int g) {
    float b[8];
    #pragma unroll
    for (int e = 0; e < 8; ++e) b[e] = rdlane(LM[e].x, J);   // L[J][g+8e]
    float2v am0 = {0.f, 0.f}, am1 = {0.f, 0.f}, am2 = {0.f, 0.f}, am3 = {0.f, 0.f};
    #pragma unroll
    for (int e = 0; e < 8; ++e) {
        float2v bb = {b[e], b[e]};
        switch (e & 3) {
            case 0: am0 += LM[e] * bb; break;     // v_pk_fma_f32
            case 1: am1 += LM[e] * bb; break;
            case 2: am2 += LM[e] * bb; break;
            default: am3 += LM[e] * bb; break;
        }
    }
    float2v part = (am0 + am1) + (am2 + am3);
    float2v* slot = pbuf + (J & 1) * 512;
    slot[g * 64 + t] = part;                      // 8B/lane stride: ~4-way, cheap
    __syncthreads();
    float2v red = ((slot[0 * 64 + t] + slot[1 * 64 + t]) + (slot[2 * 64 + t] + slot[3 * 64 + t]))
                + ((slot[4 * 64 + t] + slot[5 * 64 + t]) + (slot[6 * 64 + t] + slot[7 * 64 + t]));
    float v  = Srow[J] - red.x;
    float dj = rdlane(v, J);                      // d_J, identical in all waves
    float r  = rsqrtf(dj);
    if (g == (J & 7)) {                           // owner wave, uniform branch
        constexpr int I = J >> 3;
        float lv = (t >= J) ? v * r : 0.f;        // L[t][J]
        float mv = (t < J) ? (-red.y * r) : ((t == J) ? r : 0.f);  // M[J][t]
        LM[I] = (float2v){lv, mv};
        if (t == J) mydiag = dj;
    }
}

template <int J>
__device__ __forceinline__ void fused_run(const float (&Srow)[DDIM], float2v (&LM)[8],
                                          float2v* __restrict__ pbuf, float& mydiag,
                                          const int t, const int g) {
    fused_step<J>(Srow, LM, pbuf, mydiag, t, g);
    if constexpr (J + 1 < DDIM) fused_run<J + 1>(Srow, LM, pbuf, mydiag, t, g);
}

// ---------------------------------------------------------------------------
// Prep: 8-wave cooperative fused Cholesky+inverse, one block per component.
// grid = KCOMP blocks x 512 threads.
// ---------------------------------------------------------------------------
__global__ __launch_bounds__(512, 1) void gmm_prep(const float* __restrict__ loc,
                                                   const float* __restrict__ cov,
                                                   const float* __restrict__ pi,
                                                   _Float16* __restrict__ wt,
                                                   float* __restrict__ cstout)
{
    const int k   = blockIdx.x;
    const int tid = threadIdx.x;
    const int g   = tid >> 6;       // wave = c-subset
    const int t   = tid & 63;       // row

    __shared__ float2v pbuf[2 * 512];          // partials, parity-dbuf (8 KB)
    __shared__ float Mlds[DDIM][DDIM + 1];     // 16.6 KB
    __shared__ float mu_s[DDIM];
    __shared__ float hpart[8];

    float Srow[DDIM];    // full Sigma row t (replicated per wave)
    float2v LM[8];       // (L[t][g+8i], M[g+8i][t]) (zero-init: padding exact)

    {
        const float4* Sg = (const float4*)(cov + (size_t)k * DDIM * DDIM + (size_t)t * DDIM);
        #pragma unroll
        for (int q = 0; q < DDIM / 4; ++q) {
            float4 v = Sg[q];
            Srow[q * 4 + 0] = v.x; Srow[q * 4 + 1] = v.y;
            Srow[q * 4 + 2] = v.z; Srow[q * 4 + 3] = v.w;
        }
    }
    #pragma unroll
    for (int i = 0; i < 8; ++i) LM[i] = (float2v){0.f, 0.f};
    if (tid < DDIM) mu_s[tid] = loc[k * DDIM + tid];

    float mydiag = 1.f;   // lane t of owner wave ends holding d_t; else 1 (log=0)
    fused_run<0>(Srow, LM, pbuf, mydiag, t, g);

    // per-wave logdet partial -> LDS; M flush (wave g owns rows g+8i)
    {
        float lg = 0.5f * logf(mydiag);
        #pragma unroll
        for (int w = 1; w < 64; w <<= 1) lg += __shfl_xor(lg, w);
        if (t == 0) hpart[g] = lg;
    }
    #pragma unroll
    for (int i = 0; i < 8; ++i) Mlds[g + 8 * i][t] = LM[i].y;
    __syncthreads();

    if (tid < 64) {
        // ---- b_t = sum_j M[t][j] * mu[j] (upper of M is zero) ----
        float bt = 0.f;
        #pragma unroll 4
        for (int j = 0; j < DDIM; ++j) bt += Mlds[t][j] * mu_s[j];

        // ---- emit fragment-major f16 W~: thread t = z-row t ----
        const int r = t >> 5, lrow = t & 31;
        half8* wp = (half8*)wt;
        const size_t fbase = ((size_t)k * 2 + r) * 5;   // frag index base
        #pragma unroll
        for (int c = 0; c < 8; ++c) {          // data chunks: M row
            half8 v;
            #pragma unroll
            for (int e = 0; e < 8; ++e) v[e] = (_Float16)Mlds[t][c * 8 + e];
            int fl = lrow + 32 * (c & 1);
            wp[(fbase + (c >> 1)) * WFRAG_HALF8S + fl] = v;
        }
        {   // chunk 8 (s=4, fl=lrow): -b split hi/lo (pairs with x~=1,1)
            float nb = -bt;
            _Float16 h0 = (_Float16)nb;
            _Float16 h1 = (_Float16)(nb - (float)h0);
            half8 v;
            #pragma unroll
            for (int e = 0; e < 8; ++e) v[e] = (_Float16)0.f;
            v[0] = h0; v[1] = h1;
            wp[(fbase + 4) * WFRAG_HALF8S + lrow] = v;
        }
        {   // chunk 9 (s=4, fl=lrow+32): zeros
            half8 v;
            #pragma unroll
            for (int e = 0; e < 8; ++e) v[e] = (_Float16)0.f;
            wp[(fbase + 4) * WFRAG_HALF8S + lrow + 32] = v;
        }

        if (tid == 0) {
            float hld = ((hpart[0] + hpart[1]) + (hpart[2] + hpart[3]))
                      + ((hpart[4] + hpart[5]) + (hpart[6] + hpart[7]));
            float mxp = pi[0];
            for (int i = 1; i < KCOMP; ++i) mxp = fmaxf(mxp, pi[i]);
            float s = 0.f;
            for (int i = 0; i < KCOMP; ++i) s += __expf(pi[i] - mxp);
            float lse = mxp + logf(s);
            cstout[k] = (pi[k] - lse) - hld - 0.5f * (float)DDIM * LOG_2PI;
        }
    }
}

// ---------------------------------------------------------------------------
// Main: UNCHANGED from round 8 (MFMA-bound at ~85-90% of measured f16 peak).
// No LDS staging, no hot-loop barriers. Block = 4 waves = 4 component slices
// (8 comps each) over the SAME 128 points; W~ streams L2 -> regs dbuffered.
// ---------------------------------------------------------------------------
__global__ __launch_bounds__(256, 1) void gmm_main(const float* __restrict__ X,
                                                   const _Float16* __restrict__ wt,
                                                   const float* __restrict__ cst,
                                                   float* __restrict__ out)
{
    __shared__ float2 part[4][128];       // [slice][point] partial (mx, sm)

    const int tid  = threadIdx.x;
    const int wave = tid >> 6;            // = component slice
    const int lane = tid & 63;
    const int col  = lane & 31;
    const int h    = lane >> 5;
    const int ptbase = blockIdx.x * 128;

    // ---- build B fragments (x~) for 4 point-groups of 32 ----
    half8 bf[4][5];
    #pragma unroll
    for (int g = 0; g < 4; ++g) {
        const float* xr = X + (size_t)(ptbase + g * 32 + col) * DDIM;
        #pragma unroll
        for (int s = 0; s < 4; ++s) {
            int c = s * 2 + h;
            float4 lo = *(const float4*)(xr + c * 8);
            float4 hi = *(const float4*)(xr + c * 8 + 4);
            half8 v;
            v[0] = (_Float16)lo.x; v[1] = (_Float16)lo.y;
            v[2] = (_Float16)lo.z; v[3] = (_Float16)lo.w;
            v[4] = (_Float16)hi.x; v[5] = (_Float16)hi.y;
            v[6] = (_Float16)hi.z; v[7] = (_Float16)hi.w;
            bf[g][s] = v;
        }
        half8 v;
        #pragma unroll
        for (int e = 0; e < 8; ++e) v[e] = (_Float16)0.f;
        if (h == 0) { v[0] = (_Float16)1.f; v[1] = (_Float16)1.f; }
        bf[g][4] = v;   // augmented slice: pairs with (-b_hi, -b_lo)
    }

    const half8* wp = (const half8*)wt;
    const int comp0 = wave * 8;

    float mx[4], sm[4];
    #pragma unroll
    for (int g = 0; g < 4; ++g) { mx[g] = -INFINITY; sm[g] = 0.f; }

    half8 wfA[5], wfB[5];
    // preload tile-0 frags of first comp
    #pragma unroll
    for (int s = 0; s < 5; ++s)
        wfA[s] = wp[((size_t)comp0 * 2 + 0) * 5 * WFRAG_HALF8S + s * WFRAG_HALF8S + lane];

    #pragma unroll 1
    for (int q = 0; q < 8; ++q) {
        const int c = comp0 + q;

        // issue tile-1 frag loads (overlap with tile-0 MFMA below)
        #pragma unroll
        for (int s = 0; s < 5; ++s)
            wfB[s] = wp[((size_t)c * 2 + 1) * 5 * WFRAG_HALF8S + s * WFRAG_HALF8S + lane];

        float sP[4];

        {   // tile 0: z-rows 0..31
            floatx16 a0 = {0.f}, a1 = {0.f}, a2 = {0.f}, a3 = {0.f};
            #pragma unroll
            for (int s = 0; s < 5; ++s) {
                a0 = __builtin_amdgcn_mfma_f32_32x32x16_f16(wfA[s], bf[0][s], a0, 0, 0, 0);
                a1 = __builtin_amdgcn_mfma_f32_32x32x16_f16(wfA[s], bf[1][s], a1, 0, 0, 0);
                a2 = __builtin_amdgcn_mfma_f32_32x32x16_f16(wfA[s], bf[2][s], a2, 0, 0, 0);
                a3 = __builtin_amdgcn_mfma_f32_32x32x16_f16(wfA[s], bf[3][s], a3, 0, 0, 0);
            }
            float p0 = 0.f, p1 = 0.f, p2 = 0.f, p3 = 0.f;
            #pragma unroll
            for (int r = 0; r < 16; ++r) {
                p0 += a0[r] * a0[r]; p1 += a1[r] * a1[r];
                p2 += a2[r] * a2[r]; p3 += a3[r] * a3[r];
            }
            sP[0] = p0; sP[1] = p1; sP[2] = p2; sP[3] = p3;
        }

        // issue next comp's tile-0 loads (overlap with tile-1 MFMA below)
        if (q < 7) {
            #pragma unroll
            for (int s = 0; s < 5; ++s)
                wfA[s] = wp[((size_t)(c + 1) * 2 + 0) * 5 * WFRAG_HALF8S + s * WFRAG_HALF8S + lane];
        }

        {   // tile 1: z-rows 32..63
            floatx16 a0 = {0.f}, a1 = {0.f}, a2 = {0.f}, a3 = {0.f};
            #pragma unroll
            for (int s = 0; s < 5; ++s) {
                a0 = __builtin_amdgcn_mfma_f32_32x32x16_f16(wfB[s], bf[0][s], a0, 0, 0, 0);
                a1 = __builtin_amdgcn_mfma_f32_32x32x16_f16(wfB[s], bf[1][s], a1, 0, 0, 0);
                a2 = __builtin_amdgcn_mfma_f32_32x32x16_f16(wfB[s], bf[2][s], a2, 0, 0, 0);
                a3 = __builtin_amdgcn_mfma_f32_32x32x16_f16(wfB[s], bf[3][s], a3, 0, 0, 0);
            }
            float p0 = 0.f, p1 = 0.f, p2 = 0.f, p3 = 0.f;
            #pragma unroll
            for (int r = 0; r < 16; ++r) {
                p0 += a0[r] * a0[r]; p1 += a1[r] * a1[r];
                p2 += a2[r] * a2[r]; p3 += a3[r] * a3[r];
            }
            sP[0] += p0; sP[1] += p1; sP[2] += p2; sP[3] += p3;
        }

        const float ck = cst[c];
        #pragma unroll
        for (int g = 0; g < 4; ++g) {
            float sfull = sP[g] + __shfl_xor(sP[g], 32);
            float lp = ck - 0.5f * sfull;
            float nm = fmaxf(mx[g], lp);
            sm[g] = sm[g] * __expf(mx[g] - nm) + __expf(lp - nm);
            mx[g] = nm;
        }
    }

    // ---- merge the 4 slices in-block ----
    if (h == 0) {
        #pragma unroll
        for (int g = 0; g < 4; ++g)
            part[wave][g * 32 + col] = make_float2(mx[g], sm[g]);
    }
    __syncthreads();

    if (tid < 128) {
        float2 p0 = part[0][tid], p1 = part[1][tid];
        float2 p2 = part[2][tid], p3 = part[3][tid];
        float m = fmaxf(fmaxf(p0.x, p1.x), fmaxf(p2.x, p3.x));
        float s = p0.y * __expf(p0.x - m) + p1.y * __expf(p1.x - m)
                + p2.y * __expf(p2.x - m) + p3.y * __expf(p3.x - m);
        out[ptbase + tid] = m + logf(s);
    }
}

// ---------------------------------------------------------------------------
extern "C" void kernel_launch(void* const* d_in, const int* in_sizes, int n_in,
                              void* d_out, int out_size, void* d_ws, size_t ws_size,
                              hipStream_t stream) {
    const float* X   = (const float*)d_in[0];
    const float* loc = (const float*)d_in[1];
    const float* cov = (const float*)d_in[2];
    const float* pi  = (const float*)d_in[3];
    float* out = (float*)d_out;

    char* ws = (char*)d_ws;
    _Float16* wt = (_Float16*)ws;                              // 320 KB
    float* cstp  = (float*)(ws + (size_t)KCOMP * WCOMP_BYTES); // 128 B

    const int n = in_sizes[0] / DDIM;   // 65536

    gmm_prep<<<KCOMP, 512, 0, stream>>>(loc, cov, pi, wt, cstp);
    gmm_main<<<n / 128, 256, 0, stream>>>(X, wt, cstp, out);
}